// Round 4
// baseline (405.565 us; speedup 1.0000x reference)
//
#include <hip/hip_runtime.h>
#include <math.h>

#define B_   16
#define D_   256
#define T_   4096
#define NQn  8
#define K_   1024
#define DC_  128
#define M_   65536

typedef short bf16x8 __attribute__((ext_vector_type(8)));
typedef float f32x4  __attribute__((ext_vector_type(4)));

static __device__ __forceinline__ unsigned short f2bf(float f) {
    unsigned u = __float_as_uint(f);
    unsigned r = (u + 0x7fffu + ((u >> 16) & 1u)) >> 16;
    return (unsigned short)r;
}
static __device__ __forceinline__ float bf2f(unsigned short h) {
    return __uint_as_float(((unsigned)h) << 16);
}

__global__ void zero_acc_k(float* acc) { acc[0] = 0.f; }
__global__ void final_k(const float* __restrict__ acc, float* __restrict__ out) {
    out[0] = acc[0] * (1.f / 262144.f);   // / (4 * B * T)
}

// ---------------------------------------------------------------- transpose+convert
// X (B, D, T) f32  ->  Xb (M = B*T rows, 256 d) bf16 row-major
__global__ __launch_bounds__(256) void tr_k(
    const float* __restrict__ X, unsigned short* __restrict__ Xb)
{
    __shared__ float tile[64][65];
    const int bid = blockIdx.x;
    const int b = bid >> 8, tt = (bid >> 2) & 63, dt = bid & 3;
    const int tid = threadIdx.x;
    #pragma unroll
    for (int it = 0; it < 4; ++it) {
        int lin = it * 1024 + tid * 4;
        int dd = lin >> 6, tv = lin & 63;
        const float* src = X + ((size_t)(b * 256 + dt * 64 + dd)) * 4096 + tt * 64 + tv;
        float4 v = *(const float4*)src;
        tile[dd][tv] = v.x; tile[dd][tv + 1] = v.y;
        tile[dd][tv + 2] = v.z; tile[dd][tv + 3] = v.w;
    }
    __syncthreads();
    #pragma unroll
    for (int it = 0; it < 4; ++it) {
        int lin = it * 1024 + tid * 4;
        int tr = lin >> 6, d0 = lin & 63;
        ushort4 o;
        o.x = f2bf(tile[d0][tr]);     o.y = f2bf(tile[d0 + 1][tr]);
        o.z = f2bf(tile[d0 + 2][tr]); o.w = f2bf(tile[d0 + 3][tr]);
        *(ushort4*)&Xb[((size_t)(b * 4096 + tt * 64 + tr)) * 256 + dt * 64 + d0] = o;
    }
}

// ---------------------------------------------------------------- precompute
// F[k][d] = (embed[k]·Win[:,d]) / 64   (bf16, natural row-major)
// g[k]    = (|e_k|^2 - 2 b_in·e_k)/128
// table[k][d] = embed[k]·Wout[d] + b_out[d]   (bf16)
__global__ __launch_bounds__(256) void prep_k(
    const float* __restrict__ Win,   // (8,128,256)
    const float* __restrict__ bin,   // (8,128)
    const float* __restrict__ Wout,  // (8,256,128)
    const float* __restrict__ bout,  // (8,256)
    const float* __restrict__ emb,   // (8,1024,128)
    unsigned short* __restrict__ Fz, // (4,1024,256) bf16
    unsigned short* __restrict__ tab,// (3,1024,256) bf16
    float* __restrict__ g)           // (4,1024)
{
    __shared__ float E[16][128];
    __shared__ float sb[128];
    const int iq = blockIdx.x >> 6;
    const int k0 = (blockIdx.x & 63) << 4;
    const int tid = threadIdx.x;
    {
        const float* src = emb + ((size_t)iq * K_ + k0) * DC_;
        #pragma unroll
        for (int it = 0; it < 2; ++it) {
            int lin = it * 1024 + tid * 4;
            float4 v = *(const float4*)(src + lin);
            *(float4*)&E[lin >> 7][lin & 127] = v;
        }
        if (tid < 32) *(float4*)&sb[tid * 4] = *(const float4*)(bin + iq * DC_ + tid * 4);
    }
    __syncthreads();
    if (tid < 16) {
        float e2 = 0.f, be = 0.f;
        for (int c2 = 0; c2 < 128; ++c2) {
            float e = E[tid][c2];
            e2 += e * e; be += sb[c2] * e;
        }
        g[iq * K_ + k0 + tid] = (e2 - 2.f * be) * (1.f / 128.f);
    }
    {
        const int d = tid;
        float acc[16];
        #pragma unroll
        for (int kk = 0; kk < 16; ++kk) acc[kk] = 0.f;
        const float* wp = Win + (size_t)iq * DC_ * D_ + d;
        for (int c2 = 0; c2 < 128; ++c2) {
            float w = wp[(size_t)c2 * D_];
            #pragma unroll
            for (int kk = 0; kk < 16; ++kk) acc[kk] = fmaf(E[kk][c2], w, acc[kk]);
        }
        unsigned short* Fq = Fz + ((size_t)iq << 18);
        #pragma unroll
        for (int kk = 0; kk < 16; ++kk)
            Fq[((size_t)(k0 + kk) << 8) + d] = f2bf(acc[kk] * 0.015625f);
    }
    if (iq < 3) {
        const int d = tid;
        float acc[16];
        #pragma unroll
        for (int kk = 0; kk < 16; ++kk) acc[kk] = 0.f;
        const float* wp = Wout + ((size_t)iq * D_ + d) * DC_;
        for (int c2 = 0; c2 < 128; ++c2) {
            float w = wp[c2];
            #pragma unroll
            for (int kk = 0; kk < 16; ++kk) acc[kk] = fmaf(E[kk][c2], w, acc[kk]);
        }
        float bo = bout[iq * D_ + d];
        unsigned short* tq = tab + ((size_t)iq << 18);
        #pragma unroll
        for (int kk = 0; kk < 16; ++kk)
            tq[((size_t)(k0 + kk) << 8) + d] = f2bf(acc[kk] + bo);
    }
}

// ---------------------------------------------------------------- fused 4-quantizer RVQ, L2-direct
// 256 blocks x 256 threads (4 waves). Wave owns 64 rows (rf=4 x 16), residual
// in VGPRs. A-fragments (F codes) stream straight from L2 with reg double-buffer.
// No LDS data path, no barriers in the hot loop.

#define EPI(ACC, RF, CBB, GV) do { \
    float l0 = (ACC)[0] - (GV).x, l1 = (ACC)[1] - (GV).y; \
    float l2 = (ACC)[2] - (GV).z, l3 = (ACC)[3] - (GV).w; \
    lsum[RF] += (__expf(l0) + __expf(l1)) + (__expf(l2) + __expf(l3)); \
    float m01 = fmaxf(l0, l1), m23 = fmaxf(l2, l3); \
    float lm = fmaxf(m01, m23); \
    int jl = (m23 > m01) ? ((l3 > l2) ? 3 : 2) : ((l1 > l0) ? 1 : 0); \
    if (lm > bv[RF]) { bv[RF] = lm; bi[RF] = (CBB) + jl; } \
    if ((tgt[RF] >> 2) == ((CBB) >> 2)) { \
        int myj = tgt[RF] & 3; \
        float pj = (myj & 2) ? ((myj & 1) ? l3 : l2) : ((myj & 1) ? l1 : l0); \
        pick[RF] = pj; \
    } \
} while (0)

#define STEP(AF, CF) do { \
    float4 gv = *(const float4*)&gq[((CF) << 4) + (lg4 << 2)]; \
    f32x4 ac0 = {0.f, 0.f, 0.f, 0.f}; \
    f32x4 ac1 = ac0, ac2 = ac0, ac3 = ac0; \
    _Pragma("unroll") \
    for (int s = 0; s < 8; ++s) { \
        ac0 = __builtin_amdgcn_mfma_f32_16x16x32_bf16(AF[s], xb[0][s], ac0, 0, 0, 0); \
        ac1 = __builtin_amdgcn_mfma_f32_16x16x32_bf16(AF[s], xb[1][s], ac1, 0, 0, 0); \
        ac2 = __builtin_amdgcn_mfma_f32_16x16x32_bf16(AF[s], xb[2][s], ac2, 0, 0, 0); \
        ac3 = __builtin_amdgcn_mfma_f32_16x16x32_bf16(AF[s], xb[3][s], ac3, 0, 0, 0); \
    } \
    const int cbb = ((CF) << 4) + (lg4 << 2); \
    EPI(ac0, 0, cbb, gv); EPI(ac1, 1, cbb, gv); \
    EPI(ac2, 2, cbb, gv); EPI(ac3, 3, cbb, gv); \
} while (0)

__global__ __launch_bounds__(256, 1) void rvq_k(
    const unsigned short* __restrict__ Xb,   // (M,256) bf16
    const unsigned short* __restrict__ F,    // (4,1024,256) bf16, scaled 1/64
    const unsigned short* __restrict__ tab,  // (3,1024,256) bf16
    const float* __restrict__ g,             // (4,1024)
    const int* __restrict__ tlc,             // (B,NQ,T)
    float* __restrict__ accp)
{
    // occupancy shim: force exactly 1 block (4 waves) per CU so all 256 CUs
    // get one of the 256 blocks (no 2+0 imbalance).
    __shared__ __align__(16) char shim[81920];
    *(volatile char*)&shim[threadIdx.x] = 0;

    const int tid  = threadIdx.x;
    const int lane = tid & 63;
    const int wv   = tid >> 6;
    const int l15  = lane & 15;
    const int lg4  = lane >> 4;
    const int row_base = blockIdx.x * 256 + wv * 64;

    // residual fragments: 64 rows x 256 d, bf16, 128 VGPRs
    bf16x8 xb[4][8];
    #pragma unroll
    for (int rf = 0; rf < 4; ++rf) {
        const unsigned short* xr = Xb + (size_t)(row_base + rf * 16 + l15) * 256 + (lg4 << 3);
        #pragma unroll
        for (int s = 0; s < 8; ++s) xb[rf][s] = *(const bf16x8*)(xr + (s << 5));
    }

    float loss = 0.f;

    #pragma unroll 1
    for (int q = 0; q < 4; ++q) {
        const unsigned short* Fq = F + ((size_t)q << 18);
        const float* gq = g + (q << 10);

        int tgt[4];
        #pragma unroll
        for (int rf = 0; rf < 4; ++rf) {
            int row = row_base + rf * 16 + l15;
            tgt[rf] = tlc[(size_t)(row >> 12) * (NQn * T_) + q * T_ + (row & (T_ - 1))];
        }

        float lsum[4] = {0.f, 0.f, 0.f, 0.f};
        float bv[4]   = {-1e30f, -1e30f, -1e30f, -1e30f};
        int   bi[4]   = {0, 0, 0, 0};
        float pick[4] = {0.f, 0.f, 0.f, 0.f};

        bf16x8 afA[8], afB[8];
        {   // prefetch cf = 0
            const unsigned short* fp = Fq + (size_t)(l15) * 256 + (lg4 << 3);
            #pragma unroll
            for (int s = 0; s < 8; ++s) afA[s] = *(const bf16x8*)(fp + (s << 5));
        }

        #pragma unroll 1
        for (int c2 = 0; c2 < 32; ++c2) {
            const int cf0 = c2 * 2, cf1 = cf0 + 1;
            {   // prefetch cf1 -> afB
                const unsigned short* fp = Fq + (size_t)((cf1 << 4) + l15) * 256 + (lg4 << 3);
                #pragma unroll
                for (int s = 0; s < 8; ++s) afB[s] = *(const bf16x8*)(fp + (s << 5));
            }
            STEP(afA, cf0);
            if (c2 < 31) {   // prefetch cf0+2 -> afA
                const unsigned short* fp = Fq + (size_t)(((cf0 + 2) << 4) + l15) * 256 + (lg4 << 3);
                #pragma unroll
                for (int s = 0; s < 8; ++s) afA[s] = *(const bf16x8*)(fp + (s << 5));
            }
            STEP(afB, cf1);
        }

        // combine the 4 lg4-groups (each holds 256 of the 1024 codes per row)
        #pragma unroll
        for (int rf = 0; rf < 4; ++rf) {
            #pragma unroll
            for (int off = 16; off <= 32; off <<= 1) {
                lsum[rf] += __shfl_xor(lsum[rf], off);
                pick[rf] += __shfl_xor(pick[rf], off);
                float om = __shfl_xor(bv[rf], off);
                int   ob = __shfl_xor(bi[rf], off);
                if (om > bv[rf] || (om == bv[rf] && ob < bi[rf])) { bv[rf] = om; bi[rf] = ob; }
            }
            if (lane < 16) loss += __logf(lsum[rf]) - pick[rf];
        }

        // residual -= table[argmax]  (in-register, bf16)
        if (q < 3) {
            const unsigned short* tq = tab + ((size_t)q << 18);
            #pragma unroll
            for (int rf = 0; rf < 4; ++rf) {
                const unsigned short* trow = tq + ((size_t)bi[rf] << 8) + (lg4 << 3);
                #pragma unroll
                for (int s = 0; s < 8; ++s) {
                    bf16x8 tv = *(const bf16x8*)(trow + (s << 5));
                    bf16x8 xv = xb[rf][s];
                    #pragma unroll
                    for (int j = 0; j < 8; ++j)
                        xv[j] = (short)f2bf(bf2f((unsigned short)xv[j]) - bf2f((unsigned short)tv[j]));
                    xb[rf][s] = xv;
                }
            }
        }
        __syncthreads();   // keep the 4 waves in lockstep for L1 locality on F
    }

    #pragma unroll
    for (int off = 1; off < 64; off <<= 1) loss += __shfl_xor(loss, off);
    if (lane == 0) atomicAdd(accp, loss);
}

// ---------------------------------------------------------------- launch
extern "C" void kernel_launch(void* const* d_in, const int* in_sizes, int n_in,
                              void* d_out, int out_size, void* d_ws, size_t ws_size,
                              hipStream_t stream)
{
    (void)in_sizes; (void)n_in; (void)out_size; (void)ws_size;
    const float* dstart = (const float*)d_in[0];
    const int*   tlc    = (const int*)d_in[1];
    const float* Win    = (const float*)d_in[2];
    const float* bin    = (const float*)d_in[3];
    const float* Wout   = (const float*)d_in[4];
    const float* bout   = (const float*)d_in[5];
    const float* emb    = (const float*)d_in[6];

    char* ws = (char*)d_ws;
    size_t off = 0;
    unsigned short* Xb  = (unsigned short*)(ws + off); off += (size_t)M_ * D_ * 2;        // 33.6 MB
    unsigned short* Fz  = (unsigned short*)(ws + off); off += (size_t)4 * K_ * D_ * 2;    // 2 MB
    unsigned short* tab = (unsigned short*)(ws + off); off += (size_t)3 * K_ * D_ * 2;    // 1.5 MB
    float*          g   = (float*)(ws + off);          off += (size_t)4 * K_ * 4;
    float*          accp= (float*)(ws + off);          off += 256;

    zero_acc_k<<<1, 1, 0, stream>>>(accp);
    tr_k<<<4096, 256, 0, stream>>>(dstart, Xb);
    prep_k<<<256, 256, 0, stream>>>(Win, bin, Wout, bout, emb, Fz, tab, g);
    rvq_k<<<256, 256, 0, stream>>>(Xb, Fz, tab, g, tlc, accp);
    final_k<<<1, 1, 0, stream>>>(accp, (float*)d_out);
}